// Round 5
// baseline (802.876 us; speedup 1.0000x reference)
//
#include <hip/hip_runtime.h>
#include <hip/hip_bf16.h>
#include <math.h>

// B=16,S=1024 -> M=16384 tokens; D=1024, F=4096, E=8, R=32, SCALING=0.5
// Inputs/outputs fp32. MFMA compute in bf16 (pre-converted in ws).

#define M_TOK 16384
#define DIM_D 1024
#define DIM_F 4096
#define NEXP 8
#define RANK 32
#define NER 256  // NEXP*RANK

typedef __attribute__((ext_vector_type(8))) short bf16x8;
typedef __attribute__((ext_vector_type(4))) short bf16x4;
typedef __attribute__((ext_vector_type(4))) float f32x4;

__device__ inline short f2bs(float x) {
  __hip_bfloat16 h = __float2bfloat16(x);
  return *reinterpret_cast<short*>(&h);
}

__device__ inline void async16(const void* g, void* l) {
  __builtin_amdgcn_global_load_lds(
      (__attribute__((address_space(1))) void*)(g),
      (__attribute__((address_space(3))) void*)(l), 16, 0, 0);
}

// ---------------- K_conv: 6 regions fp32 -> bf16 in one dispatch ----------------
struct Conv6 {
  const float* src[6];
  short* dst[6];
  int base[6];  // exclusive prefix sums, in 8-elem chunks
  int total;    // total chunks
};

__global__ __launch_bounds__(256) void convert6(Conv6 c) {
  const int i = blockIdx.x * 256 + threadIdx.x;
  if (i >= c.total) return;
  int r = 0;
#pragma unroll
  for (int k = 1; k < 6; ++k) r += (i >= c.base[k]);
  const int j = i - c.base[r];
  const float4* p = (const float4*)c.src[r] + 2 * (size_t)j;
  float4 u = p[0], v = p[1];
  bf16x8 o;
  o[0] = f2bs(u.x); o[1] = f2bs(u.y); o[2] = f2bs(u.z); o[3] = f2bs(u.w);
  o[4] = f2bs(v.x); o[5] = f2bs(v.y); o[6] = f2bs(v.z); o[7] = f2bs(v.w);
  *(bf16x8*)(c.dst[r] + 8 * (size_t)j) = o;
}

// ---------------- K0: router (one wave per token, fp32; also emits bf16 x) ----------------
__global__ __launch_bounds__(256) void router_kernel(
    const float* __restrict__ X,     // [M, D]
    const float* __restrict__ RW,    // [E, D]
    const float* __restrict__ RB,    // [E]
    float* __restrict__ routing_out, // [M, E]
    float* __restrict__ ec_out,      // [M, E]
    int* __restrict__ idx_out,       // [M]
    short* __restrict__ xb)          // [M, D] bf16
{
  const int wave = threadIdx.x >> 6;
  const int lane = threadIdx.x & 63;
  const int t = blockIdx.x * 4 + wave;

  const float4* xp = (const float4*)(X + (size_t)t * DIM_D);
  float4 xv[4];
#pragma unroll
  for (int i = 0; i < 4; ++i) xv[i] = xp[lane + 64 * i];

  // bf16 copy of x (row-major, same layout)
#pragma unroll
  for (int i = 0; i < 4; ++i) {
    bf16x4 o;
    o[0] = f2bs(xv[i].x); o[1] = f2bs(xv[i].y);
    o[2] = f2bs(xv[i].z); o[3] = f2bs(xv[i].w);
    *(bf16x4*)(xb + (size_t)t * DIM_D + 4 * (lane + 64 * i)) = o;
  }

  float logit[NEXP];
#pragma unroll
  for (int e = 0; e < NEXP; ++e) {
    const float4* wp = (const float4*)(RW + (size_t)e * DIM_D);
    double p = 0.0;
#pragma unroll
    for (int i = 0; i < 4; ++i) {
      float4 w = wp[lane + 64 * i];
      p += (double)xv[i].x * w.x + (double)xv[i].y * w.y +
           (double)xv[i].z * w.z + (double)xv[i].w * w.w;
    }
#pragma unroll
    for (int off = 32; off > 0; off >>= 1) p += __shfl_xor(p, off);
    logit[e] = (float)p + RB[e];
  }
  float m = logit[0];
  int am = 0;
#pragma unroll
  for (int e = 1; e < NEXP; ++e)
    if (logit[e] > m) { m = logit[e]; am = e; }
  float pr[NEXP], s = 0.f;
#pragma unroll
  for (int e = 0; e < NEXP; ++e) { pr[e] = expf(logit[e] - m); s += pr[e]; }
  const float inv = 1.f / s;
  if (lane < NEXP) {
    float r = pr[lane] * inv;
    routing_out[(size_t)t * NEXP + lane] = r;
    float y = (lane == am) ? 1.f : 0.f;
    ec_out[(size_t)t * NEXP + lane] = (y - r) + r;
  }
  if (lane == 0) idx_out[t] = am;
}

// ---------------- main bf16 MFMA GEMM C = A * Bm^T (+LoRA K-tail) ----------------
// 128x128 tile, 4 waves (2x2), per-wave 64x64 via 4x4 mfma_f32_16x16x32_bf16.
// EPI: 0 = fp32 out, +bias+0.5*LB[e];  1 = bf16 out, gelu(+bias+0.5*LB[e])
template <int KMAIN, int EPI>
__global__ __launch_bounds__(256, 2) void gemm_bf16(
    const short* __restrict__ A, const short* __restrict__ Bm,
    const short* __restrict__ G2, const short* __restrict__ LW,
    const float* __restrict__ LB, const float* __restrict__ bias,
    const int* __restrict__ idx, void* __restrict__ outv, int N)
{
  __shared__ __align__(16) short As[128 * 32];
  __shared__ __align__(16) short Bs[128 * 32];

  const int tid = threadIdx.x;
  const int m0 = blockIdx.y * 128;
  const int n0 = blockIdx.x * 128;
  const int lane = tid & 63;
  const int wv = tid >> 6;
  const int quad = lane >> 4;
  const int lrow = lane & 15;
  const int wr = wv >> 1;
  const int wc = wv & 1;
  const int r0 = tid >> 2;
  const int c4 = (tid & 3) * 8;

  f32x4 acc[4][4];
#pragma unroll
  for (int i = 0; i < 4; ++i)
#pragma unroll
    for (int j = 0; j < 4; ++j) acc[i][j] = (f32x4){0.f, 0.f, 0.f, 0.f};

  // ---- main K loop: simple pointer increments (no branch inside) ----
  const short* ap = A + (size_t)(m0 + r0) * KMAIN + c4;
  const short* bp = Bm + (size_t)(n0 + r0) * KMAIN + c4;
  for (int it = 0; it < KMAIN / 32; ++it) {
    async16(ap, &As[tid * 8]);
    async16(ap + (size_t)64 * KMAIN, &As[2048 + tid * 8]);
    async16(bp, &Bs[tid * 8]);
    async16(bp + (size_t)64 * KMAIN, &Bs[2048 + tid * 8]);
    ap += 32;
    bp += 32;
    __syncthreads();

    bf16x8 af[4], bfv[4];
#pragma unroll
    for (int i = 0; i < 4; ++i)
      af[i] = *(const bf16x8*)&As[(wr * 64 + i * 16 + lrow) * 32 + quad * 8];
#pragma unroll
    for (int j = 0; j < 4; ++j)
      bfv[j] = *(const bf16x8*)&Bs[(wc * 64 + j * 16 + lrow) * 32 + quad * 8];
#pragma unroll
    for (int i = 0; i < 4; ++i)
#pragma unroll
      for (int j = 0; j < 4; ++j)
        acc[i][j] = __builtin_amdgcn_mfma_f32_16x16x32_bf16(af[i], bfv[j],
                                                            acc[i][j], 0, 0, 0);
    __syncthreads();
  }

  // ---- LoRA K-tail: 8 experts x K=32 ----
  {
    const short* gp = G2 + (size_t)(m0 + r0) * NER + c4;
    const short* lp = LW + (size_t)(n0 + r0) * RANK + c4;
    for (int e = 0; e < NEXP; ++e) {
      async16(gp, &As[tid * 8]);
      async16(gp + 64 * NER, &As[2048 + tid * 8]);
      async16(lp, &Bs[tid * 8]);
      async16(lp + 64 * RANK, &Bs[2048 + tid * 8]);
      gp += RANK;
      lp += (size_t)N * RANK;
      __syncthreads();

      bf16x8 af[4], bfv[4];
#pragma unroll
      for (int i = 0; i < 4; ++i)
        af[i] = *(const bf16x8*)&As[(wr * 64 + i * 16 + lrow) * 32 + quad * 8];
#pragma unroll
      for (int j = 0; j < 4; ++j)
        bfv[j] = *(const bf16x8*)&Bs[(wc * 64 + j * 16 + lrow) * 32 + quad * 8];
#pragma unroll
      for (int i = 0; i < 4; ++i)
#pragma unroll
        for (int j = 0; j < 4; ++j)
          acc[i][j] = __builtin_amdgcn_mfma_f32_16x16x32_bf16(af[i], bfv[j],
                                                              acc[i][j], 0, 0, 0);
      __syncthreads();
    }
  }

  float cb[4];
#pragma unroll
  for (int j = 0; j < 4; ++j) cb[j] = bias[n0 + wc * 64 + j * 16 + lrow];

#pragma unroll
  for (int i = 0; i < 4; ++i) {
#pragma unroll
    for (int reg = 0; reg < 4; ++reg) {
      const int t = m0 + wr * 64 + i * 16 + quad * 4 + reg;
      const int e = idx[t];
#pragma unroll
      for (int j = 0; j < 4; ++j) {
        const int gc = n0 + wc * 64 + j * 16 + lrow;
        float v = acc[i][j][reg] + cb[j] + 0.5f * LB[(size_t)e * N + gc];
        if (EPI == 1) {
          v = 0.5f * v * (1.0f + erff(v * 0.70710678118654752f));
          ((short*)outv)[(size_t)t * N + gc] = f2bs(v);
        } else {
          ((float*)outv)[(size_t)t * N + gc] = v;
        }
      }
    }
  }
}

// ---------------- LoRA-A GEMM: 128x64 tile, g2 = mask(0.5*(A . W^T + b)) ----------------
// A [M,K] bf16, W [256,K] bf16 -> g2 [M,256] bf16. 4 waves as 2x2, wave 64x32 (4x2 frags).
template <int KMAIN>
__global__ __launch_bounds__(256, 2) void lora_a_gemm(
    const short* __restrict__ A, const short* __restrict__ W,
    const float* __restrict__ bias,  // [256]
    const int* __restrict__ idx, short* __restrict__ g2)
{
  __shared__ __align__(16) short As[128 * 32];
  __shared__ __align__(16) short Bs[64 * 32];

  const int tid = threadIdx.x;
  const int m0 = blockIdx.y * 128;
  const int n0 = blockIdx.x * 64;
  const int lane = tid & 63;
  const int wv = tid >> 6;
  const int quad = lane >> 4;
  const int lrow = lane & 15;
  const int wr = wv >> 1;  // 0..1 : 64-row halves
  const int wc = wv & 1;   // 0..1 : 32-col halves
  const int r0 = tid >> 2;
  const int c4 = (tid & 3) * 8;

  f32x4 acc[4][2];
#pragma unroll
  for (int i = 0; i < 4; ++i)
#pragma unroll
    for (int j = 0; j < 2; ++j) acc[i][j] = (f32x4){0.f, 0.f, 0.f, 0.f};

  const short* ap = A + (size_t)(m0 + r0) * KMAIN + c4;
  const short* bp = W + (size_t)(n0 + r0) * KMAIN + c4;
  for (int it = 0; it < KMAIN / 32; ++it) {
    async16(ap, &As[tid * 8]);
    async16(ap + (size_t)64 * KMAIN, &As[2048 + tid * 8]);
    async16(bp, &Bs[tid * 8]);  // 64 rows x 32 = 4 KB exactly
    ap += 32;
    bp += 32;
    __syncthreads();

    bf16x8 af[4], bfv[2];
#pragma unroll
    for (int i = 0; i < 4; ++i)
      af[i] = *(const bf16x8*)&As[(wr * 64 + i * 16 + lrow) * 32 + quad * 8];
#pragma unroll
    for (int j = 0; j < 2; ++j)
      bfv[j] = *(const bf16x8*)&Bs[(wc * 32 + j * 16 + lrow) * 32 + quad * 8];
#pragma unroll
    for (int i = 0; i < 4; ++i)
#pragma unroll
      for (int j = 0; j < 2; ++j)
        acc[i][j] = __builtin_amdgcn_mfma_f32_16x16x32_bf16(af[i], bfv[j],
                                                            acc[i][j], 0, 0, 0);
    __syncthreads();
  }

  float cb[2];
#pragma unroll
  for (int j = 0; j < 2; ++j) cb[j] = bias[n0 + wc * 32 + j * 16 + lrow];

#pragma unroll
  for (int i = 0; i < 4; ++i) {
#pragma unroll
    for (int reg = 0; reg < 4; ++reg) {
      const int t = m0 + wr * 64 + i * 16 + quad * 4 + reg;
      const int e = idx[t];
#pragma unroll
      for (int j = 0; j < 2; ++j) {
        const int gc = n0 + wc * 32 + j * 16 + lrow;
        float v = ((gc >> 5) == e) ? 0.5f * (acc[i][j][reg] + cb[j]) : 0.f;
        g2[(size_t)t * NER + gc] = f2bs(v);
      }
    }
  }
}

extern "C" void kernel_launch(void* const* d_in, const int* in_sizes, int n_in,
                              void* d_out, int out_size, void* d_ws, size_t ws_size,
                              hipStream_t stream) {
  (void)in_sizes; (void)n_in; (void)out_size; (void)ws_size;
  const float* x        = (const float*)d_in[0];
  const float* router_w = (const float*)d_in[1];
  const float* router_b = (const float*)d_in[2];
  const float* fc1_w    = (const float*)d_in[3];
  const float* fc1_b    = (const float*)d_in[4];
  const float* fc2_w    = (const float*)d_in[5];
  const float* fc2_b    = (const float*)d_in[6];
  const float* down_A_w = (const float*)d_in[7];
  const float* down_A_b = (const float*)d_in[8];
  const float* down_B_w = (const float*)d_in[9];
  const float* down_B_b = (const float*)d_in[10];
  const float* up_A_w   = (const float*)d_in[11];
  const float* up_A_b   = (const float*)d_in[12];
  const float* up_B_w   = (const float*)d_in[13];
  const float* up_B_b   = (const float*)d_in[14];

  char* ws = (char*)d_ws;
  size_t off = 0;
  int* idxp = (int*)ws;                    off += (size_t)M_TOK * 4;
  short* g2d  = (short*)(ws + off);        off += (size_t)M_TOK * NER * 2;
  short* g2u  = (short*)(ws + off);        off += (size_t)M_TOK * NER * 2;
  short* a_ws = (short*)(ws + off);        off += (size_t)M_TOK * DIM_F * 2;
  short* xb   = (short*)(ws + off);        off += (size_t)M_TOK * DIM_D * 2;
  short* fc1b = (short*)(ws + off);        off += (size_t)DIM_F * DIM_D * 2;
  short* fc2b = (short*)(ws + off);        off += (size_t)DIM_D * DIM_F * 2;
  short* dAb  = (short*)(ws + off);        off += (size_t)NER * DIM_D * 2;
  short* uAb  = (short*)(ws + off);        off += (size_t)NER * DIM_F * 2;
  short* dBb  = (short*)(ws + off);        off += (size_t)NEXP * DIM_F * RANK * 2;
  short* uBb  = (short*)(ws + off);        off += (size_t)NEXP * DIM_D * RANK * 2;

  float* out = (float*)d_out;
  float* routing = out + (size_t)M_TOK * DIM_D;
  float* ec = routing + (size_t)M_TOK * NEXP;

  // router + x->bf16
  router_kernel<<<M_TOK / 4, 256, 0, stream>>>(x, router_w, router_b, routing,
                                               ec, idxp, xb);

  // 6 weight conversions in one dispatch
  Conv6 c;
  const float* srcs[6] = {fc1_w, fc2_w, down_A_w, up_A_w, down_B_w, up_B_w};
  short* dsts[6] = {fc1b, fc2b, dAb, uAb, dBb, uBb};
  const size_t ns[6] = {(size_t)DIM_F * DIM_D, (size_t)DIM_D * DIM_F,
                        (size_t)NER * DIM_D,   (size_t)NER * DIM_F,
                        (size_t)NEXP * DIM_F * RANK, (size_t)NEXP * DIM_D * RANK};
  int acc8 = 0;
  for (int i = 0; i < 6; ++i) {
    c.src[i] = srcs[i];
    c.dst[i] = dsts[i];
    c.base[i] = acc8;
    acc8 += (int)(ns[i] / 8);
  }
  c.total = acc8;
  convert6<<<(c.total + 255) / 256, 256, 0, stream>>>(c);

  // LoRA-A down: g2d = mask(0.5*(xb . dAb^T + b))
  lora_a_gemm<DIM_D><<<dim3(NER / 64, M_TOK / 128), 256, 0, stream>>>(
      xb, dAb, down_A_b, idxp, g2d);
  // GEMM1: a_ws = gelu(xb . fc1b^T + fc1_b + LoRA-B(down))
  gemm_bf16<DIM_D, 1><<<dim3(DIM_F / 128, M_TOK / 128), 256, 0, stream>>>(
      xb, fc1b, g2d, dBb, down_B_b, fc1_b, idxp, a_ws, DIM_F);
  // LoRA-A up: g2u = mask(0.5*(a_ws . uAb^T + b))
  lora_a_gemm<DIM_F><<<dim3(NER / 64, M_TOK / 128), 256, 0, stream>>>(
      a_ws, uAb, up_A_b, idxp, g2u);
  // GEMM2: out = a_ws . fc2b^T + fc2_b + LoRA-B(up)  (fp32 out)
  gemm_bf16<DIM_F, 0><<<dim3(DIM_D / 128, M_TOK / 128), 256, 0, stream>>>(
      a_ws, fc2b, g2u, uBb, up_B_b, fc2_b, idxp, out, DIM_D);
}